// Round 1
// baseline (4775.297 us; speedup 1.0000x reference)
//
#include <hip/hip_runtime.h>
#include <cstdint>

#define B_SZ   2048
#define T_SZ   80
#define VOCABN 80
#define EMBN   8
#define HID    256
#define G4     1024
#define TILE   16
#define NBLK   (B_SZ / TILE)   // 128
#define NWAVE  8
#define NTHR   (NWAVE * 64)    // 512

typedef __bf16 bf16;
typedef __attribute__((ext_vector_type(8))) __bf16 bf16x8;
typedef __attribute__((ext_vector_type(4))) float  f32x4;

__device__ __forceinline__ float sigf(float x)   { return 1.0f / (1.0f + __expf(-x)); }
__device__ __forceinline__ float tanhf2(float x) { return 1.0f - 2.0f / (__expf(2.0f * x) + 1.0f); }

__device__ __forceinline__ unsigned short f2bf(float f) {
    union { float f; unsigned int u; } v; v.f = f;
    unsigned int u = v.u;
    return (unsigned short)((u + 0x7FFFu + ((u >> 16) & 1u)) >> 16);
}

// ws layout:
//   eg  : float [80][1024]          327680 B   (emb@W1_x + b1, per-vocab gate bias)
//   w1p : bf16  [64][8][64][8]      524288 B   (W1_h packed in B-frag order)
//   w2p : bf16  [64][16][64][8]    1048576 B   (W2 packed; k 0..7 = h1 rows, 8..15 = h2 rows)

__global__ void prep_eg(const float* __restrict__ emb, const float* __restrict__ W1,
                        const float* __restrict__ b1, float* __restrict__ eg) {
    int idx = blockIdx.x * blockDim.x + threadIdx.x;
    if (idx >= VOCABN * G4) return;
    int v = idx >> 10, n = idx & 1023;
    float s = b1[n];
#pragma unroll
    for (int e = 0; e < EMBN; ++e) s += emb[v * EMBN + e] * W1[e * G4 + n];
    eg[idx] = s;
}

__global__ void prep_w1(const float* __restrict__ W1, unsigned short* __restrict__ w1p) {
    int idx = blockIdx.x * blockDim.x + threadIdx.x;     // nt(64) x k(8) x lane(64)
    if (idx >= 64 * 8 * 64) return;
    int lane = idx & 63, k = (idx >> 6) & 7, nt = idx >> 9;
    int scol = (nt << 4) + (lane & 15);
    int r0 = EMBN + k * 32 + ((lane >> 4) << 3);
#pragma unroll
    for (int e = 0; e < 8; ++e)
        w1p[idx * 8 + e] = f2bf(W1[(r0 + e) * G4 + scol]);
}

__global__ void prep_w2(const float* __restrict__ W2, unsigned short* __restrict__ w2p) {
    int idx = blockIdx.x * blockDim.x + threadIdx.x;     // nt(64) x k(16) x lane(64)
    if (idx >= 64 * 16 * 64) return;
    int lane = idx & 63, k = (idx >> 6) & 15, nt = idx >> 10;
    int scol = (nt << 4) + (lane & 15);
    int r0 = k * 32 + ((lane >> 4) << 3);
#pragma unroll
    for (int e = 0; e < 8; ++e)
        w2p[idx * 8 + e] = f2bf(W2[(r0 + e) * G4 + scol]);
}

__global__ __launch_bounds__(NTHR, 2)
void lstm_fused(const int* __restrict__ feat, const int* __restrict__ labels,
                const float* __restrict__ eg,
                const unsigned short* __restrict__ w1p,
                const unsigned short* __restrict__ w2p,
                const float* __restrict__ b2,
                const float* __restrict__ Wd, const float* __restrict__ bd,
                float* __restrict__ out)
{
    __shared__ __align__(16) bf16 h1s[TILE][HID + 8];
    __shared__ __align__(16) bf16 h2s[TILE][HID + 8];
    __shared__ int   toks[TILE][T_SZ];
    __shared__ float logitb[TILE][VOCABN + 4];
    __shared__ float lossb[TILE];

    const int tid  = threadIdx.x;
    const int lane = tid & 63;
    const int wid  = tid >> 6;     // wave id 0..7: owns h-cols [wid*32, wid*32+32)
    const int lc   = lane & 15;
    const int lg   = lane >> 4;
    const int b0   = blockIdx.x * TILE;

    for (int i = tid; i < TILE * (HID + 8); i += NTHR) {
        (&h1s[0][0])[i] = (bf16)0.0f;
        (&h2s[0][0])[i] = (bf16)0.0f;
    }
    for (int i = tid; i < TILE * T_SZ; i += NTHR) {
        int r = i / T_SZ, t = i - r * T_SZ;
        toks[r][t] = feat[(b0 + r) * T_SZ + t];
    }
    __syncthreads();

    const bf16x8* w1v = (const bf16x8*)w1p;
    const bf16x8* w2v = (const bf16x8*)w2p;

    const f32x4 zf = {0.f, 0.f, 0.f, 0.f};
    f32x4 c1a[2], c2a[2];
    c1a[0] = zf; c1a[1] = zf; c2a[0] = zf; c2a[1] = zf;

    float b2r[4][2];
#pragma unroll
    for (int g = 0; g < 4; ++g)
#pragma unroll
        for (int d = 0; d < 2; ++d)
            b2r[g][d] = b2[g * 256 + wid * 32 + d * 16 + lc];

    for (int t = 0; t < T_SZ; ++t) {
        // ---- phase A: load A-fragments of h1_{t-1}, h2_{t-1} ----
        bf16x8 a1[8], a2h[8];
#pragma unroll
        for (int k = 0; k < 8; ++k) {
            a1[k]  = *(const bf16x8*)&h1s[lc][k * 32 + lg * 8];
            a2h[k] = *(const bf16x8*)&h2s[lc][k * 32 + lg * 8];
        }
        __syncthreads();

        // ---- phase B: layer-1 gates = h1_{t-1} @ W1h (+ emb_gates lookup) ----
        f32x4 acc[4][2];
#pragma unroll
        for (int g = 0; g < 4; ++g) { acc[g][0] = zf; acc[g][1] = zf; }
#pragma unroll
        for (int g = 0; g < 4; ++g)
#pragma unroll
            for (int d = 0; d < 2; ++d) {
                const int nt = g * 16 + 2 * wid + d;
                const bf16x8* bp = w1v + nt * 8 * 64 + lane;
#pragma unroll
                for (int k = 0; k < 8; ++k)
                    acc[g][d] = __builtin_amdgcn_mfma_f32_16x16x32_bf16(a1[k], bp[k * 64], acc[g][d], 0, 0, 0);
            }
#pragma unroll
        for (int d = 0; d < 2; ++d) {
            const int hcol = wid * 32 + d * 16 + lc;
#pragma unroll
            for (int r = 0; r < 4; ++r) {
                const int row = lg * 4 + r;
                const int tok = toks[row][t];
                const float* egr = eg + tok * G4 + hcol;
                float gi = acc[0][d][r] + egr[0];
                float gj = acc[1][d][r] + egr[256];
                float gf = acc[2][d][r] + egr[512];
                float go = acc[3][d][r] + egr[768];
                float c  = c1a[d][r];
                float cn = c * sigf(gf + 1.0f) + sigf(gi) * tanhf2(gj);
                float h  = tanhf2(cn) * sigf(go);
                c1a[d][r] = cn;
                h1s[row][hcol] = (bf16)h;
            }
        }
        __syncthreads();

        // ---- phase C: layer-2 gates = [h1_t, h2_{t-1}] @ W2 ----
        bf16x8 a2x[8];
#pragma unroll
        for (int k = 0; k < 8; ++k)
            a2x[k] = *(const bf16x8*)&h1s[lc][k * 32 + lg * 8];
#pragma unroll
        for (int g = 0; g < 4; ++g) { acc[g][0] = zf; acc[g][1] = zf; }
#pragma unroll
        for (int g = 0; g < 4; ++g)
#pragma unroll
            for (int d = 0; d < 2; ++d) {
                const int nt = g * 16 + 2 * wid + d;
                const bf16x8* bp = w2v + nt * 16 * 64 + lane;
#pragma unroll
                for (int k = 0; k < 8; ++k)
                    acc[g][d] = __builtin_amdgcn_mfma_f32_16x16x32_bf16(a2x[k], bp[k * 64], acc[g][d], 0, 0, 0);
#pragma unroll
                for (int k = 0; k < 8; ++k)
                    acc[g][d] = __builtin_amdgcn_mfma_f32_16x16x32_bf16(a2h[k], bp[(k + 8) * 64], acc[g][d], 0, 0, 0);
            }
#pragma unroll
        for (int d = 0; d < 2; ++d) {
            const int hcol = wid * 32 + d * 16 + lc;
#pragma unroll
            for (int r = 0; r < 4; ++r) {
                const int row = lg * 4 + r;
                float gi = acc[0][d][r] + b2r[0][d];
                float gj = acc[1][d][r] + b2r[1][d];
                float gf = acc[2][d][r] + b2r[2][d];
                float go = acc[3][d][r] + b2r[3][d];
                float c  = c2a[d][r];
                float cn = c * sigf(gf + 1.0f) + sigf(gi) * tanhf2(gj);
                float h  = tanhf2(cn) * sigf(go);
                c2a[d][r] = cn;
                h2s[row][hcol] = (bf16)h;
            }
        }
        __syncthreads();
    }

    // ---- epilogue: logits = h2_last @ Wd + bd, log-softmax NLL, mean ----
    for (int p = tid; p < TILE * VOCABN; p += NTHR) {
        int row = p / VOCABN, v = p - row * VOCABN;
        float s = bd[v];
        for (int k = 0; k < HID; ++k)
            s += (float)h2s[row][k] * Wd[k * VOCABN + v];
        logitb[row][v] = s;
    }
    __syncthreads();
    if (tid < TILE) {
        const int row = tid;
        float m = -1e30f;
        for (int v = 0; v < VOCABN; ++v) m = fmaxf(m, logitb[row][v]);
        float s = 0.f;
        for (int v = 0; v < VOCABN; ++v) s += __expf(logitb[row][v] - m);
        int lab = labels[b0 + row];
        lossb[row] = m + __logf(s) - logitb[row][lab];
    }
    __syncthreads();
    if (tid == 0) {
        float s = 0.f;
#pragma unroll
        for (int r = 0; r < TILE; ++r) s += lossb[r];
        atomicAdd(out, s * (1.0f / (float)B_SZ));
    }
}

extern "C" void kernel_launch(void* const* d_in, const int* in_sizes, int n_in,
                              void* d_out, int out_size, void* d_ws, size_t ws_size,
                              hipStream_t stream)
{
    (void)in_sizes; (void)n_in; (void)out_size; (void)ws_size;
    const int*   feat   = (const int*)d_in[0];
    const int*   labels = (const int*)d_in[1];
    const float* emb    = (const float*)d_in[2];
    const float* W1     = (const float*)d_in[3];
    const float* b1     = (const float*)d_in[4];
    const float* W2     = (const float*)d_in[5];
    const float* b2     = (const float*)d_in[6];
    const float* Wd     = (const float*)d_in[7];
    const float* bd     = (const float*)d_in[8];
    float* out = (float*)d_out;

    char* ws = (char*)d_ws;
    float*          eg  = (float*)ws;                               // 327680 B
    unsigned short* w1p = (unsigned short*)(ws + 327680);           // 524288 B
    unsigned short* w2p = (unsigned short*)(ws + 327680 + 524288);  // 1048576 B

    hipMemsetAsync(d_out, 0, sizeof(float), stream);
    prep_eg<<<(VOCABN * G4 + 255) / 256, 256, 0, stream>>>(emb, W1, b1, eg);
    prep_w1<<<(64 * 8 * 64) / 256, 256, 0, stream>>>(W1, w1p);
    prep_w2<<<(64 * 16 * 64) / 256, 256, 0, stream>>>(W2, w2p);
    lstm_fused<<<NBLK, NTHR, 0, stream>>>(feat, labels, eg, w1p, w2p, b2, Wd, bd, out);
}